// Round 1
// baseline (161.350 us; speedup 1.0000x reference)
//
#include <hip/hip_runtime.h>

typedef unsigned short u16;
typedef unsigned int u32;
typedef __attribute__((ext_vector_type(8))) short short8;
typedef __attribute__((ext_vector_type(4))) float f32x4;

#define LOG2E 1.4426950408889634f
#define RSQRT_MD 0.04419417382415922f

__device__ __forceinline__ u16 f2bf(float f) {
  u32 u = __builtin_bit_cast(u32, f);
  u32 r = u + 0x7fffu + ((u >> 16) & 1u);
  return (u16)(r >> 16);
}

__device__ __forceinline__ uint4 pack8(float4 a, float4 b) {
  uint4 c;
  c.x = (u32)f2bf(a.x) | ((u32)f2bf(a.y) << 16);
  c.y = (u32)f2bf(a.z) | ((u32)f2bf(a.w) << 16);
  c.z = (u32)f2bf(b.x) | ((u32)f2bf(b.y) << 16);
  c.w = (u32)f2bf(b.z) | ((u32)f2bf(b.w) << 16);
  return c;
}

__device__ __forceinline__ f32x4 vmax4(f32x4 a, f32x4 b) {
  f32x4 r;
#pragma unroll
  for (int i = 0; i < 4; ++i) r[i] = fmaxf(a[i], b[i]);
  return r;
}

__device__ __forceinline__ f32x4 shflx4(f32x4 v, int m) {
  f32x4 r;
#pragma unroll
  for (int i = 0; i < 4; ++i) r[i] = __shfl_xor(v[i], m);
  return r;
}

// LDS tile layout: rows of 64 bf16 = 8 chunks of 16B; chunk index XOR-swizzled
// by (row&7) to keep 16B alignment AND <=2-way bank aliasing (free, m136).
__device__ __forceinline__ int sw_idx(int row, int chunk) {
  return row * 64 + ((chunk ^ (row & 7)) * 8);
}

// ---------------- Kernel 1: weight prep ----------------
// wcat[192][512] bf16: rows 0-63 Wq^T * (log2e/sqrt(512)), 64-127 Wk^T, 128-191 Wv^T
// wot[512][64] bf16: WoSum^T, wot[d][e] = sum_h Wo[h*64+e][d]
__global__ __launch_bounds__(256) void prep(
    const float* __restrict__ Wq, const float* __restrict__ Wk,
    const float* __restrict__ Wv, const float* __restrict__ Wo,
    u16* __restrict__ wcat, u16* __restrict__ wot) {
  int idx = blockIdx.x * 256 + threadIdx.x;
  if (idx < 3 * 64 * 512) {
    int row = idx >> 9, k = idx & 511;
    int mat = row >> 6, n = row & 63;
    const float* W = (mat == 0) ? Wq : ((mat == 1) ? Wk : Wv);
    float scale = (mat == 0) ? (LOG2E * RSQRT_MD) : 1.0f;
    wcat[idx] = f2bf(W[k * 64 + n] * scale);
  } else {
    int j = idx - 3 * 64 * 512;
    int d = j >> 6, e = j & 63;
    float s = 0.f;
#pragma unroll
    for (int h = 0; h < 8; ++h) s += Wo[(size_t)(h * 64 + e) * 512 + d];
    wot[j] = f2bf(s);
  }
}

// ---------------- Kernel 2: QKV projection ----------------
// C[16384 x 192] = x[16384 x 512] @ Wcat[512 x 192]; Q,K row-major bf16, V transposed [B][64][S]
__global__ __launch_bounds__(256) void qkv_proj(
    const float* __restrict__ x, const u16* __restrict__ wcat,
    u16* __restrict__ Q, u16* __restrict__ K, u16* __restrict__ V) {
  __shared__ __align__(16) u16 xt[64 * 64];
  __shared__ __align__(16) u16 wt[192 * 64];
  const int t = threadIdx.x;
  const int lane = t & 63, wv = t >> 6;
  const int quad = lane >> 4, ml = lane & 15;
  const int m0 = blockIdx.x * 64;
  const int rw = (wv & 1) * 32;   // wave row base (32 rows)
  const int cw = (wv >> 1) * 96;  // wave col base (96 cols)
  const int sr = t >> 2, sc4 = t & 3;

  f32x4 acc[2][6];
#pragma unroll
  for (int i = 0; i < 2; ++i)
#pragma unroll
    for (int j = 0; j < 6; ++j) acc[i][j] = (f32x4)0.0f;

  for (int kt = 0; kt < 8; ++kt) {
    __syncthreads();
    {  // stage x tile [64 rows][64 k] fp32 -> bf16
      const float* xp = x + (size_t)(m0 + sr) * 512 + kt * 64 + sc4 * 16;
      float4 f0 = *(const float4*)(xp);
      float4 f1 = *(const float4*)(xp + 4);
      float4 f2 = *(const float4*)(xp + 8);
      float4 f3 = *(const float4*)(xp + 12);
      int cb = sc4 * 2;
      *(uint4*)&xt[sw_idx(sr, cb)] = pack8(f0, f1);
      *(uint4*)&xt[sw_idx(sr, cb + 1)] = pack8(f2, f3);
    }
#pragma unroll
    for (int i = 0; i < 3; ++i) {  // stage w tile [192 rows][64 k]
      int row = i * 64 + sr;
      const u16* wp = wcat + (size_t)row * 512 + kt * 64 + sc4 * 16;
      uint4 a0 = *(const uint4*)(wp);
      uint4 a1 = *(const uint4*)(wp + 8);
      int cb = sc4 * 2;
      *(uint4*)&wt[sw_idx(row, cb)] = a0;
      *(uint4*)&wt[sw_idx(row, cb + 1)] = a1;
    }
    __syncthreads();
#pragma unroll
    for (int kc = 0; kc < 2; ++kc) {
      short8 a[2], b[6];
#pragma unroll
      for (int rg = 0; rg < 2; ++rg) {
        int row = rw + rg * 16 + ml;
        a[rg] = *(const short8*)&xt[sw_idx(row, kc * 4 + quad)];
      }
#pragma unroll
      for (int nt = 0; nt < 6; ++nt) {
        int row = cw + nt * 16 + ml;
        b[nt] = *(const short8*)&wt[sw_idx(row, kc * 4 + quad)];
      }
#pragma unroll
      for (int rg = 0; rg < 2; ++rg)
#pragma unroll
        for (int nt = 0; nt < 6; ++nt)
          acc[rg][nt] = __builtin_amdgcn_mfma_f32_16x16x32_bf16(a[rg], b[nt], acc[rg][nt], 0, 0, 0);
    }
  }
  // epilogue: C rows = quad*4+r, cols = lane&15 (verified m89/m91 layout)
#pragma unroll
  for (int rg = 0; rg < 2; ++rg) {
#pragma unroll
    for (int nt = 0; nt < 6; ++nt) {
      int n = cw + nt * 16 + ml;
#pragma unroll
      for (int r = 0; r < 4; ++r) {
        int m = m0 + rw + rg * 16 + quad * 4 + r;
        u16 hv = f2bf(acc[rg][nt][r]);
        if (n < 64) {
          Q[(size_t)m * 64 + n] = hv;
        } else if (n < 128) {
          K[(size_t)m * 64 + (n - 64)] = hv;
        } else {
          int d = n - 128, bb = m >> 11, s = m & 2047;
          V[((size_t)bb * 64 + d) * 2048 + s] = hv;
        }
      }
    }
  }
}

// ---------------- Kernel 3: fused flash attention + output projection ----------------
__global__ __launch_bounds__(256) void attn_out(
    const u16* __restrict__ Q, const u16* __restrict__ K,
    const u16* __restrict__ V, const u16* __restrict__ WoT,
    float* __restrict__ out) {
  __shared__ __align__(16) u16 qt[64 * 64];
  __shared__ __align__(16) u16 ktile[64 * 64];
  __shared__ __align__(16) u16 vtile[64 * 64];
  __shared__ __align__(16) u16 pt[4][16 * 64];
  const int t = threadIdx.x, lane = t & 63, wv = t >> 6;
  const int quad = lane >> 4, ml = lane & 15;
  const int b = blockIdx.x >> 5;
  const int q0 = (blockIdx.x & 31) * 64;
  const int sr = t >> 2, sc4 = t & 3;

  {  // stage Q tile once
    const u16* qp = Q + (size_t)(b * 2048 + q0 + sr) * 64 + sc4 * 16;
    uint4 a0 = *(const uint4*)qp;
    uint4 a1 = *(const uint4*)(qp + 8);
    int cb = sc4 * 2;
    *(uint4*)&qt[sw_idx(sr, cb)] = a0;
    *(uint4*)&qt[sw_idx(sr, cb + 1)] = a1;
  }
  __syncthreads();
  short8 qf[2];
  {
    int row = wv * 16 + ml;
    qf[0] = *(const short8*)&qt[sw_idx(row, quad)];
    qf[1] = *(const short8*)&qt[sw_idx(row, 4 + quad)];
  }
  f32x4 z[4];
#pragma unroll
  for (int i = 0; i < 4; ++i) z[i] = (f32x4)0.0f;
  f32x4 mrow = (f32x4)(-1e30f);
  f32x4 lrow = (f32x4)0.0f;

  for (int it = 0; it < 32; ++it) {
    __syncthreads();  // protect k/v tiles from previous iteration readers
    {                 // stage K [64 keys][64 d] and V^T [64 d][64 keys]
      const u16* kp = K + (size_t)(b * 2048 + it * 64 + sr) * 64 + sc4 * 16;
      uint4 a0 = *(const uint4*)kp;
      uint4 a1 = *(const uint4*)(kp + 8);
      int cb = sc4 * 2;
      *(uint4*)&ktile[sw_idx(sr, cb)] = a0;
      *(uint4*)&ktile[sw_idx(sr, cb + 1)] = a1;
      const u16* vp = V + (size_t)(b * 64 + sr) * 2048 + it * 64 + sc4 * 16;
      uint4 b0 = *(const uint4*)vp;
      uint4 b1 = *(const uint4*)(vp + 8);
      *(uint4*)&vtile[sw_idx(sr, cb)] = b0;
      *(uint4*)&vtile[sw_idx(sr, cb + 1)] = b1;
    }
    __syncthreads();
    // scores: S[16 q][64 keys] per wave (q rows = wv*16..+15)
    f32x4 sc[4];
#pragma unroll
    for (int g = 0; g < 4; ++g) sc[g] = (f32x4)0.0f;
#pragma unroll
    for (int kc = 0; kc < 2; ++kc) {
#pragma unroll
      for (int g = 0; g < 4; ++g) {
        int row = g * 16 + ml;
        short8 kb = *(const short8*)&ktile[sw_idx(row, kc * 4 + quad)];
        sc[g] = __builtin_amdgcn_mfma_f32_16x16x32_bf16(qf[kc], kb, sc[g], 0, 0, 0);
      }
    }
    // online softmax (base-2; log2e folded into Wq)
    f32x4 mx = vmax4(vmax4(sc[0], sc[1]), vmax4(sc[2], sc[3]));
    for (int s = 1; s < 16; s <<= 1) mx = vmax4(mx, shflx4(mx, s));
    f32x4 mnew = vmax4(mrow, mx);
    f32x4 alpha, rs;
#pragma unroll
    for (int r = 0; r < 4; ++r) {
      alpha[r] = __builtin_amdgcn_exp2f(mrow[r] - mnew[r]);
      rs[r] = 0.f;
    }
#pragma unroll
    for (int g = 0; g < 4; ++g)
#pragma unroll
      for (int r = 0; r < 4; ++r) {
        float p = __builtin_amdgcn_exp2f(sc[g][r] - mnew[r]);
        sc[g][r] = p;
        rs[r] += p;
      }
    for (int s = 1; s < 16; s <<= 1) rs = rs + shflx4(rs, s);
    lrow = lrow * alpha + rs;
    mrow = mnew;
#pragma unroll
    for (int nt = 0; nt < 4; ++nt) z[nt] = z[nt] * alpha;
    // P: C-layout -> A-layout via per-wave LDS round trip (m120 pattern)
#pragma unroll
    for (int g = 0; g < 4; ++g)
#pragma unroll
      for (int r = 0; r < 4; ++r) {
        int key = g * 16 + ml, row = quad * 4 + r;
        pt[wv][sw_idx(row, key >> 3) + (key & 7)] = f2bf(sc[g][r]);
      }
    // PV: z[16 q][64 d] += P[16 q][64 keys] @ V[64 keys][64 d]
#pragma unroll
    for (int kc = 0; kc < 2; ++kc) {
      short8 pa = *(const short8*)&pt[wv][sw_idx(ml, kc * 4 + quad)];
#pragma unroll
      for (int nt = 0; nt < 4; ++nt) {
        int vrow = nt * 16 + ml;
        short8 vb = *(const short8*)&vtile[sw_idx(vrow, kc * 4 + quad)];
        z[nt] = __builtin_amdgcn_mfma_f32_16x16x32_bf16(pa, vb, z[nt], 0, 0, 0);
      }
    }
  }
  // finalize softmax denominator
  f32x4 rl;
#pragma unroll
  for (int r = 0; r < 4; ++r) rl[r] = 1.0f / lrow[r];
#pragma unroll
  for (int nt = 0; nt < 4; ++nt) z[nt] = z[nt] * rl;
  // z (C-layout) -> A-layout via pt[wv]
#pragma unroll
  for (int nt = 0; nt < 4; ++nt)
#pragma unroll
    for (int r = 0; r < 4; ++r) {
      int col = nt * 16 + ml, row = quad * 4 + r;
      pt[wv][sw_idx(row, col >> 3) + (col & 7)] = f2bf(z[nt][r]);
    }
  short8 zf[2];
  zf[0] = *(const short8*)&pt[wv][sw_idx(ml, quad)];
  zf[1] = *(const short8*)&pt[wv][sw_idx(ml, 4 + quad)];
  // fused output projection: out[16 q][512] = z[16 q][64] @ WoSum[64][512]
  const size_t orow0 = (size_t)(b * 2048 + q0 + wv * 16 + quad * 4);
  for (int nt2 = 0; nt2 < 32; ++nt2) {
    f32x4 o = (f32x4)0.0f;
#pragma unroll
    for (int kc = 0; kc < 2; ++kc) {
      short8 wb = *(const short8*)&WoT[(size_t)(nt2 * 16 + ml) * 64 + kc * 32 + quad * 8];
      o = __builtin_amdgcn_mfma_f32_16x16x32_bf16(zf[kc], wb, o, 0, 0, 0);
    }
#pragma unroll
    for (int r = 0; r < 4; ++r)
      out[(orow0 + r) * 512 + nt2 * 16 + ml] = o[r];
  }
}

extern "C" void kernel_launch(void* const* d_in, const int* in_sizes, int n_in,
                              void* d_out, int out_size, void* d_ws, size_t ws_size,
                              hipStream_t stream) {
  const float* x = (const float*)d_in[0];
  const float* Wq = (const float*)d_in[1];
  const float* Wk = (const float*)d_in[2];
  const float* Wv = (const float*)d_in[3];
  const float* Wo = (const float*)d_in[4];
  float* out = (float*)d_out;

  u16* wcat = (u16*)d_ws;          // [192][512]
  u16* wot = wcat + 192 * 512;     // [512][64]
  u16* Q = wot + 512 * 64;         // [16384][64]
  u16* K = Q + 16384 * 64;         // [16384][64]
  u16* V = K + 16384 * 64;         // [8][64][2048]

  hipLaunchKernelGGL(prep, dim3(512), dim3(256), 0, stream, Wq, Wk, Wv, Wo, wcat, wot);
  hipLaunchKernelGGL(qkv_proj, dim3(256), dim3(256), 0, stream, x, wcat, Q, K, V);
  hipLaunchKernelGGL(attn_out, dim3(256), dim3(256), 0, stream, Q, K, V, wot, out);
}

// Round 2
// 138.197 us; speedup vs baseline: 1.1675x; 1.1675x over previous
//
#include <hip/hip_runtime.h>

typedef unsigned short u16;
typedef unsigned int u32;
typedef __attribute__((ext_vector_type(8))) short short8;
typedef __attribute__((ext_vector_type(4))) float f32x4;

#define LOG2E 1.4426950408889634f
#define RSQRT_MD 0.04419417382415922f

__device__ __forceinline__ u16 f2bf(float f) {
  u32 u = __builtin_bit_cast(u32, f);
  u32 r = u + 0x7fffu + ((u >> 16) & 1u);
  return (u16)(r >> 16);
}

__device__ __forceinline__ uint4 pack8(float4 a, float4 b) {
  uint4 c;
  c.x = (u32)f2bf(a.x) | ((u32)f2bf(a.y) << 16);
  c.y = (u32)f2bf(a.z) | ((u32)f2bf(a.w) << 16);
  c.z = (u32)f2bf(b.x) | ((u32)f2bf(b.y) << 16);
  c.w = (u32)f2bf(b.z) | ((u32)f2bf(b.w) << 16);
  return c;
}

__device__ __forceinline__ f32x4 vmax4(f32x4 a, f32x4 b) {
  f32x4 r;
#pragma unroll
  for (int i = 0; i < 4; ++i) r[i] = fmaxf(a[i], b[i]);
  return r;
}

__device__ __forceinline__ f32x4 shflx4(f32x4 v, int m) {
  f32x4 r;
#pragma unroll
  for (int i = 0; i < 4; ++i) r[i] = __shfl_xor(v[i], m);
  return r;
}

// LDS tile: rows of 64 bf16 = 8 chunks of 16B, chunk XOR-swizzled by row&7
// (16B-aligned, <=2-way bank aliasing which is free, m136).
__device__ __forceinline__ int swo(int row, int chunk) {
  return row * 64 + ((chunk ^ (row & 7)) * 8);
}

// ---------------- Kernel 1: weight prep ----------------
// wcat[192][512] bf16: rows 0-63 Wq^T * (log2e/sqrt(512)), 64-127 Wk^T, 128-191 Wv^T
// wot[512][64] bf16: WoSum^T, wot[d][e] = sum_h Wo[h*64+e][d]
__global__ __launch_bounds__(256) void prep(
    const float* __restrict__ Wq, const float* __restrict__ Wk,
    const float* __restrict__ Wv, const float* __restrict__ Wo,
    u16* __restrict__ wcat, u16* __restrict__ wot) {
  int idx = blockIdx.x * 256 + threadIdx.x;
  if (idx < 3 * 64 * 512) {
    int row = idx >> 9, k = idx & 511;
    int mat = row >> 6, n = row & 63;
    const float* W = (mat == 0) ? Wq : ((mat == 1) ? Wk : Wv);
    float scale = (mat == 0) ? (LOG2E * RSQRT_MD) : 1.0f;
    wcat[idx] = f2bf(W[k * 64 + n] * scale);
  } else {
    int j = idx - 3 * 64 * 512;
    int d = j >> 6, e = j & 63;
    float s = 0.f;
#pragma unroll
    for (int h = 0; h < 8; ++h) s += Wo[(size_t)(h * 64 + e) * 512 + d];
    wot[j] = f2bf(s);
  }
}

// ---------------- Kernel 2: QKV projection ----------------
// 32-row tiles, grid 512 (2 blocks/CU). Each wave: 32 rows x 48 cols.
// Q,K row-major bf16; V transposed [B][64][S] with packed ushort4 stores.
__global__ __launch_bounds__(256) void qkv_proj(
    const float* __restrict__ x, const u16* __restrict__ wcat,
    u16* __restrict__ Q, u16* __restrict__ K, u16* __restrict__ V) {
  __shared__ __align__(16) u16 xt[32 * 64];
  __shared__ __align__(16) u16 wt[192 * 64];
  const int t = threadIdx.x;
  const int lane = t & 63, wv = t >> 6;
  const int quad = lane >> 4, ml = lane & 15;
  const int m0 = blockIdx.x * 32;
  const int cw = wv * 48;
  const int xr = t >> 3, xc = t & 7;
  const int wr = t >> 2, wc = t & 3;

  f32x4 acc[2][3];
#pragma unroll
  for (int i = 0; i < 2; ++i)
#pragma unroll
    for (int j = 0; j < 3; ++j) acc[i][j] = (f32x4)0.0f;

  for (int kt = 0; kt < 8; ++kt) {
    __syncthreads();
    {  // stage x tile [32 rows][64 k] fp32 -> bf16 (one 16B chunk per thread)
      const float* xp = x + (size_t)(m0 + xr) * 512 + kt * 64 + xc * 8;
      float4 f0 = *(const float4*)(xp);
      float4 f1 = *(const float4*)(xp + 4);
      *(uint4*)&xt[swo(xr, xc)] = pack8(f0, f1);
    }
#pragma unroll
    for (int i = 0; i < 3; ++i) {  // stage w tile [192 rows][64 k]
      int row = i * 64 + wr;
      const u16* wp = wcat + (size_t)row * 512 + kt * 64 + wc * 16;
      uint4 a0 = *(const uint4*)(wp);
      uint4 a1 = *(const uint4*)(wp + 8);
      *(uint4*)&wt[swo(row, wc * 2)] = a0;
      *(uint4*)&wt[swo(row, wc * 2 + 1)] = a1;
    }
    __syncthreads();
#pragma unroll
    for (int kc = 0; kc < 2; ++kc) {
      short8 a[2], b[3];
#pragma unroll
      for (int sub = 0; sub < 2; ++sub)
        a[sub] = *(const short8*)&xt[swo(sub * 16 + ml, kc * 4 + quad)];
#pragma unroll
      for (int nt = 0; nt < 3; ++nt)
        b[nt] = *(const short8*)&wt[swo(cw + nt * 16 + ml, kc * 4 + quad)];
#pragma unroll
      for (int sub = 0; sub < 2; ++sub)
#pragma unroll
        for (int nt = 0; nt < 3; ++nt)
          acc[sub][nt] = __builtin_amdgcn_mfma_f32_16x16x32_bf16(a[sub], b[nt], acc[sub][nt], 0, 0, 0);
    }
  }
  // epilogue: C rows = quad*4+r, cols = lane&15
#pragma unroll
  for (int sub = 0; sub < 2; ++sub) {
    const int mrow = m0 + sub * 16 + quad * 4;
#pragma unroll
    for (int nt = 0; nt < 3; ++nt) {
      int n = cw + nt * 16 + ml;
      if (n < 128) {
        u16* dst = (n < 64) ? (Q + (size_t)mrow * 64 + n)
                            : (K + (size_t)mrow * 64 + (n - 64));
#pragma unroll
        for (int r = 0; r < 4; ++r) dst[(size_t)r * 64] = f2bf(acc[sub][nt][r]);
      } else {
        int d = n - 128;
        int bb = m0 >> 11;
        int s0 = (m0 & 2047) + sub * 16 + quad * 4;
        ushort4 pk;
        pk.x = f2bf(acc[sub][nt][0]);
        pk.y = f2bf(acc[sub][nt][1]);
        pk.z = f2bf(acc[sub][nt][2]);
        pk.w = f2bf(acc[sub][nt][3]);
        *(ushort4*)&V[((size_t)(bb * 64 + d)) * 2048 + s0] = pk;
      }
    }
  }
}

// ---------------- Kernel 3: flash attention + output projection ----------------
// Block = 32 Q rows; 4 waves split the 2048 keys into 512-key quarters.
// Barrier-free main loop (direct global fragment loads); in-block LDS merge.
__global__ __launch_bounds__(256) void attn_out(
    const u16* __restrict__ Q, const u16* __restrict__ K,
    const u16* __restrict__ VT, const u16* __restrict__ WoT,
    float* __restrict__ out) {
  __shared__ __align__(16) u16 pt[4][16 * 64];       // per-wave P staging
  __shared__ __align__(16) float zp[4][32][68];      // partial z (padded)
  __shared__ float mp[4][32], lp[4][32];
  __shared__ __align__(16) u16 zb[32 * 64];          // merged z, bf16
  const int t = threadIdx.x, lane = t & 63, wv = t >> 6;
  const int quad = lane >> 4, ml = lane & 15;
  const int b = blockIdx.x >> 6;
  const int q0 = (blockIdx.x & 63) * 32;

  // Q fragments: direct global load (A-layout: lane=row, quad*8=k)
  const u16* Qb = Q + ((size_t)(b * 2048 + q0)) * 64;
  short8 qf[2][2];
#pragma unroll
  for (int sub = 0; sub < 2; ++sub)
#pragma unroll
    for (int kc = 0; kc < 2; ++kc)
      qf[sub][kc] = *(const short8*)&Qb[(sub * 16 + ml) * 64 + kc * 32 + quad * 8];

  f32x4 z[2][4];
#pragma unroll
  for (int i = 0; i < 2; ++i)
#pragma unroll
    for (int j = 0; j < 4; ++j) z[i][j] = (f32x4)0.0f;
  f32x4 m[2], l[2];
#pragma unroll
  for (int i = 0; i < 2; ++i) {
    m[i] = (f32x4)(-1e30f);
    l[i] = (f32x4)0.0f;
  }

  const u16* Kb = K + ((size_t)(b * 2048 + wv * 512)) * 64;
  const u16* Vb = VT + ((size_t)(b * 64)) * 2048 + wv * 512;

  for (int it = 0; it < 8; ++it) {
    // K fragments (B-layout: lane=key, quad*8=k=d), 16 rows x 64B coalesced
    short8 kb[2][4];
#pragma unroll
    for (int kc = 0; kc < 2; ++kc)
#pragma unroll
      for (int g = 0; g < 4; ++g)
        kb[kc][g] = *(const short8*)&Kb[(size_t)(it * 64 + g * 16 + ml) * 64 + kc * 32 + quad * 8];
    f32x4 sc[2][4];
#pragma unroll
    for (int i = 0; i < 2; ++i)
#pragma unroll
      for (int j = 0; j < 4; ++j) sc[i][j] = (f32x4)0.0f;
#pragma unroll
    for (int kc = 0; kc < 2; ++kc)
#pragma unroll
      for (int sub = 0; sub < 2; ++sub)
#pragma unroll
        for (int g = 0; g < 4; ++g)
          sc[sub][g] = __builtin_amdgcn_mfma_f32_16x16x32_bf16(qf[sub][kc], kb[kc][g], sc[sub][g], 0, 0, 0);
    // V^T fragments (B-layout: lane=d, quad*8=k=key)
    short8 vb[2][4];
#pragma unroll
    for (int kc = 0; kc < 2; ++kc)
#pragma unroll
      for (int nt = 0; nt < 4; ++nt)
        vb[kc][nt] = *(const short8*)&Vb[(size_t)(nt * 16 + ml) * 2048 + it * 64 + kc * 32 + quad * 8];

#pragma unroll
    for (int sub = 0; sub < 2; ++sub) {
      f32x4 mx = vmax4(vmax4(sc[sub][0], sc[sub][1]), vmax4(sc[sub][2], sc[sub][3]));
      for (int s = 1; s < 16; s <<= 1) mx = vmax4(mx, shflx4(mx, s));
      f32x4 mnew = vmax4(m[sub], mx);
      f32x4 alpha, rs;
#pragma unroll
      for (int r = 0; r < 4; ++r) {
        alpha[r] = __builtin_amdgcn_exp2f(m[sub][r] - mnew[r]);
        rs[r] = 0.f;
      }
#pragma unroll
      for (int g = 0; g < 4; ++g)
#pragma unroll
        for (int r = 0; r < 4; ++r) {
          float p = __builtin_amdgcn_exp2f(sc[sub][g][r] - mnew[r]);
          sc[sub][g][r] = p;
          rs[r] += p;
        }
      for (int s = 1; s < 16; s <<= 1) rs = rs + shflx4(rs, s);
      l[sub] = l[sub] * alpha + rs;
      m[sub] = mnew;
#pragma unroll
      for (int nt = 0; nt < 4; ++nt) z[sub][nt] = z[sub][nt] * alpha;
      // P: C-layout -> A-layout via per-wave LDS round trip (in-wave order)
#pragma unroll
      for (int g = 0; g < 4; ++g)
#pragma unroll
        for (int r = 0; r < 4; ++r) {
          int row = quad * 4 + r;
          pt[wv][row * 64 + (((g * 2 + (ml >> 3)) ^ (row & 7)) * 8) + (ml & 7)] = f2bf(sc[sub][g][r]);
        }
#pragma unroll
      for (int kc = 0; kc < 2; ++kc) {
        short8 pa = *(const short8*)&pt[wv][swo(ml, kc * 4 + quad)];
#pragma unroll
        for (int nt = 0; nt < 4; ++nt)
          z[sub][nt] = __builtin_amdgcn_mfma_f32_16x16x32_bf16(pa, vb[kc][nt], z[sub][nt], 0, 0, 0);
      }
    }
  }
  // write partials
#pragma unroll
  for (int sub = 0; sub < 2; ++sub) {
    int qq = sub * 16 + quad * 4;
#pragma unroll
    for (int nt = 0; nt < 4; ++nt)
#pragma unroll
      for (int r = 0; r < 4; ++r) zp[wv][qq + r][nt * 16 + ml] = z[sub][nt][r];
    if (ml == 0) {
#pragma unroll
      for (int r = 0; r < 4; ++r) {
        mp[wv][qq + r] = m[sub][r];
        lp[wv][qq + r] = l[sub][r];
      }
    }
  }
  __syncthreads();
  {  // merge 4 key-quarter partials; thread t -> (q = t>>3, 8 d's)
    int q = t >> 3, c8 = t & 7;
    float mv0 = mp[0][q], mv1 = mp[1][q], mv2 = mp[2][q], mv3 = mp[3][q];
    float M = fmaxf(fmaxf(mv0, mv1), fmaxf(mv2, mv3));
    float aw[4];
    aw[0] = __builtin_amdgcn_exp2f(mv0 - M);
    aw[1] = __builtin_amdgcn_exp2f(mv1 - M);
    aw[2] = __builtin_amdgcn_exp2f(mv2 - M);
    aw[3] = __builtin_amdgcn_exp2f(mv3 - M);
    float L = aw[0] * lp[0][q] + aw[1] * lp[1][q] + aw[2] * lp[2][q] + aw[3] * lp[3][q];
    float rl = 1.0f / L;
    f32x4 acc0 = (f32x4)0.0f, acc1 = (f32x4)0.0f;
#pragma unroll
    for (int w = 0; w < 4; ++w) {
      f32x4 z0 = *(const f32x4*)&zp[w][q][c8 * 8];
      f32x4 z1 = *(const f32x4*)&zp[w][q][c8 * 8 + 4];
      acc0 = acc0 + z0 * aw[w];
      acc1 = acc1 + z1 * aw[w];
    }
    acc0 = acc0 * rl;
    acc1 = acc1 * rl;
    short8 pk;
#pragma unroll
    for (int j = 0; j < 4; ++j) {
      pk[j] = (short)f2bf(acc0[j]);
      pk[4 + j] = (short)f2bf(acc1[j]);
    }
    *(short8*)&zb[q * 64 + ((c8 ^ (q & 7)) * 8)] = pk;
  }
  __syncthreads();
  // fused output projection: out[32 q][512] = z[32][64] @ WoSum[64][512]
  short8 zf[2][2];
#pragma unroll
  for (int sub = 0; sub < 2; ++sub)
#pragma unroll
    for (int kc = 0; kc < 2; ++kc)
      zf[sub][kc] = *(const short8*)&zb[swo(sub * 16 + ml, kc * 4 + quad)];
  const size_t ob = (size_t)(b * 2048 + q0);
#pragma unroll
  for (int nt2 = 0; nt2 < 8; ++nt2) {
    int col0 = wv * 128 + nt2 * 16;
    short8 wb0 = *(const short8*)&WoT[(size_t)(col0 + ml) * 64 + quad * 8];
    short8 wb1 = *(const short8*)&WoT[(size_t)(col0 + ml) * 64 + 32 + quad * 8];
#pragma unroll
    for (int sub = 0; sub < 2; ++sub) {
      f32x4 o = (f32x4)0.0f;
      o = __builtin_amdgcn_mfma_f32_16x16x32_bf16(zf[sub][0], wb0, o, 0, 0, 0);
      o = __builtin_amdgcn_mfma_f32_16x16x32_bf16(zf[sub][1], wb1, o, 0, 0, 0);
#pragma unroll
      for (int r = 0; r < 4; ++r)
        out[(ob + sub * 16 + quad * 4 + r) * 512 + col0 + ml] = o[r];
    }
  }
}

extern "C" void kernel_launch(void* const* d_in, const int* in_sizes, int n_in,
                              void* d_out, int out_size, void* d_ws, size_t ws_size,
                              hipStream_t stream) {
  const float* x = (const float*)d_in[0];
  const float* Wq = (const float*)d_in[1];
  const float* Wk = (const float*)d_in[2];
  const float* Wv = (const float*)d_in[3];
  const float* Wo = (const float*)d_in[4];
  float* out = (float*)d_out;

  u16* wcat = (u16*)d_ws;          // [192][512]
  u16* wot = wcat + 192 * 512;     // [512][64]
  u16* Q = wot + 512 * 64;         // [16384][64]
  u16* K = Q + 16384 * 64;         // [16384][64]
  u16* V = K + 16384 * 64;         // [8][64][2048] (V^T per batch)

  hipLaunchKernelGGL(prep, dim3(512), dim3(256), 0, stream, Wq, Wk, Wv, Wo, wcat, wot);
  hipLaunchKernelGGL(qkv_proj, dim3(512), dim3(256), 0, stream, x, wcat, Q, K, V);
  hipLaunchKernelGGL(attn_out, dim3(512), dim3(256), 0, stream, Q, K, V, wot, out);
}